// Round 1
// 99.965 us; speedup vs baseline: 1.1127x; 1.1127x over previous
//
#include <hip/hip_runtime.h>
#include <math.h>

// Problem constants
#define BB 2
#define HH 64
#define WW 64
#define CC 192
#define NH 6
#define HD 32
#define KS 7
#define NPIX (BB * HH * WW)          // 8192
#define SCALE 0.17677669529663687f   // 1/sqrt(32)
#define GK 192                       // K dim for both GEMMs

typedef __attribute__((ext_vector_type(8))) _Float16 f16x8;
typedef __attribute__((ext_vector_type(2))) _Float16 f16x2;
typedef __attribute__((ext_vector_type(4))) float    f32x4;

#define LDA 200   // halves stride for As/Bs staging tiles
#define CST 68    // dword stride for f32 C repack tile (272B, 16B-aligned rows)

__device__ __forceinline__ f16x2 u2h(unsigned u) {
    union { unsigned u; f16x2 h; } c; c.u = u; return c.h;
}

__device__ __forceinline__ float hdot2(f16x2 a, f16x2 b, float c) {
#if __has_builtin(__builtin_amdgcn_fdot2)
    return __builtin_amdgcn_fdot2(a, b, c, false);
#else
    return fmaf((float)a[1], (float)b[1], fmaf((float)a[0], (float)b[0], c));
#endif
}

// ---------------------------------------------------------------------------
// GEMM1: qkv[8192,576] (fp16) = x[8192,192] (f32) @ w_qkv[576,192]^T
// q columns (col0 < 192) pre-scaled by SCALE in the epilogue.
// 64x64 tile, 4 waves, 2x2 MFMA 16x16x32 f16. fp16 C written coalesced via
// an LDS f32 repack (reuses As).  1D grid, XCD-chunked: 1152 = 8 XCD * 144.
// ---------------------------------------------------------------------------
__global__ __launch_bounds__(256) void gemm_qkv(const float* __restrict__ A,
                                                const float* __restrict__ Bw,
                                                _Float16* __restrict__ Cm) {
    __shared__ __align__(16) _Float16 As[64 * LDA];
    __shared__ __align__(16) _Float16 Bs[64 * LDA];

    const int t  = threadIdx.x;
    const int s  = blockIdx.x;           // 0..1151
    const int kk = s >> 3;               // 0..143
    const int rowblk = (s & 7) * 16 + kk / 9;   // same-row tiles share an XCD
    const int colblk = kk % 9;
    const int row0 = rowblk * 64;
    const int col0 = colblk * 64;

    // ---- stage A,B tiles: 64 rows x 192 fp32 -> fp16 ----
#pragma unroll
    for (int it = 0; it < 6; ++it) {
        const int idx = t + it * 256;
        const int r   = idx / 24;
        const int c8  = (idx % 24) * 8;
        const float* pa = A  + (size_t)(row0 + r) * GK + c8;
        const float* pb = Bw + (size_t)(col0 + r) * GK + c8;
        float4 a0 = *(const float4*)pa;
        float4 a1 = *(const float4*)(pa + 4);
        float4 b0 = *(const float4*)pb;
        float4 b1 = *(const float4*)(pb + 4);
        f16x8 ha, hb;
        ha[0] = (_Float16)a0.x; ha[1] = (_Float16)a0.y;
        ha[2] = (_Float16)a0.z; ha[3] = (_Float16)a0.w;
        ha[4] = (_Float16)a1.x; ha[5] = (_Float16)a1.y;
        ha[6] = (_Float16)a1.z; ha[7] = (_Float16)a1.w;
        hb[0] = (_Float16)b0.x; hb[1] = (_Float16)b0.y;
        hb[2] = (_Float16)b0.z; hb[3] = (_Float16)b0.w;
        hb[4] = (_Float16)b1.x; hb[5] = (_Float16)b1.y;
        hb[6] = (_Float16)b1.z; hb[7] = (_Float16)b1.w;
        *(f16x8*)&As[r * LDA + c8] = ha;
        *(f16x8*)&Bs[r * LDA + c8] = hb;
    }
    __syncthreads();

    const int wave = t >> 6;
    const int wr   = wave >> 1;
    const int wc   = wave & 1;
    const int lane = t & 63;
    const int ln   = lane & 15;
    const int quad = lane >> 4;

    f32x4 acc[2][2] = {};

#pragma unroll
    for (int ks = 0; ks < 6; ++ks) {
        const int k0 = ks * 32 + quad * 8;
        f16x8 af[2], bf[2];
#pragma unroll
        for (int mi = 0; mi < 2; ++mi)
            af[mi] = *(const f16x8*)&As[(wr * 32 + mi * 16 + ln) * LDA + k0];
#pragma unroll
        for (int ni = 0; ni < 2; ++ni)
            bf[ni] = *(const f16x8*)&Bs[(wc * 32 + ni * 16 + ln) * LDA + k0];
#pragma unroll
        for (int mi = 0; mi < 2; ++mi)
#pragma unroll
            for (int ni = 0; ni < 2; ++ni)
                acc[mi][ni] = __builtin_amdgcn_mfma_f32_16x16x32_f16(
                    af[mi], bf[ni], acc[mi][ni], 0, 0, 0);
    }

    // ---- epilogue: acc -> LDS f32 tile -> coalesced fp16 global writes ----
    __syncthreads();                    // all waves done reading As/Bs
    float* Cs = (float*)As;             // 64 x CST f32 = 17.4 KB < 25.6 KB
#pragma unroll
    for (int mi = 0; mi < 2; ++mi)
#pragma unroll
        for (int ni = 0; ni < 2; ++ni) {
            const int col = wc * 32 + ni * 16 + ln;
#pragma unroll
            for (int r = 0; r < 4; ++r) {
                const int row = wr * 32 + mi * 16 + quad * 4 + r;
                Cs[row * CST + col] = acc[mi][ni][r];
            }
        }
    __syncthreads();

    const float sc = (col0 < 192) ? SCALE : 1.f;   // fold q * scale
#pragma unroll
    for (int it = 0; it < 2; ++it) {
        const int idx = t + it * 256;   // 0..511
        const int r   = idx >> 3;
        const int c8  = (idx & 7) * 8;
        const float* src = Cs + r * CST + c8;
        float4 f0 = *(const float4*)src;
        float4 f1 = *(const float4*)(src + 4);
        f16x8 hv;
        hv[0] = (_Float16)(f0.x * sc); hv[1] = (_Float16)(f0.y * sc);
        hv[2] = (_Float16)(f0.z * sc); hv[3] = (_Float16)(f0.w * sc);
        hv[4] = (_Float16)(f1.x * sc); hv[5] = (_Float16)(f1.y * sc);
        hv[6] = (_Float16)(f1.z * sc); hv[7] = (_Float16)(f1.w * sc);
        *(f16x8*)&Cm[(size_t)(row0 + r) * 576 + col0 + c8] = hv;
    }
}

// ---------------------------------------------------------------------------
// natten_v3: block = (b, head, qrow), 256 threads = 4 warps.
// qkv is fp16 (q pre-scaled). K/V staged in LDS transposed: [16 pair-chunks]
// [64 px] with stride 66 dwords -> conflict-free reads. Dot via v_dot2_f32_f16
// with 4 independent chains. Output written as fp16.
// XCD-chunked grid: 768 = 8 * 96 (neighboring qrows share K/V in one L2).
// ---------------------------------------------------------------------------
#define KSTR 66
#define VOFFD 1056
#define PSTRF 34

__global__ __launch_bounds__(256, 3) void natten_v3(const _Float16* __restrict__ qkv,
                                                    const float* __restrict__ rpb,
                                                    const float* __restrict__ temperature,
                                                    _Float16* __restrict__ attn) {
    const int tid  = threadIdx.x;
    const int w    = tid >> 6;
    const int j    = tid & 63;
    const int s    = blockIdx.x;
    const int g    = (s & 7) * 96 + (s >> 3);   // XCD-chunked remap (bijective)
    const int i    = g & 63;
    const int head = (g >> 6) % NH;
    const int b    = g / (64 * NH);

    __shared__ unsigned region[4][2176];   // per-warp: K [16][66] | V [16][66]
    __shared__ float srpb[169];
    if (tid < 169) srpb[tid] = rpb[head * 169 + tid];

    const float temp = temperature[head];
    const size_t pix = (size_t)b * 4096 + i * 64 + j;
    const _Float16* qp = qkv + pix * 576 + head * HD;

    f16x2 q2[16];
#pragma unroll
    for (int c8 = 0; c8 < 4; ++c8) {
        f16x8 qv = *(const f16x8*)(qp + c8 * 8);
#pragma unroll
        for (int p2 = 0; p2 < 4; ++p2) {
            f16x2 tmp;
            tmp[0] = qv[p2 * 2 + 0];
            tmp[1] = qv[p2 * 2 + 1];
            q2[c8 * 4 + p2] = tmp;
        }
    }

    __syncthreads();   // srpb visible

    const int si = min(max(i - 3, 0), HH - KS);
    const int sj = min(max(j - 3, 0), WW - KS);

    float m = -1e30f, l = 0.f;
    float acc[HD];
#pragma unroll
    for (int d = 0; d < HD; ++d) acc[d] = 0.f;

    unsigned* kreg = region[w];
    unsigned* vreg = region[w] + VOFFD;

    const int nrows = (w < 3) ? 2 : 1;
    for (int t = 0; t < nrows; ++t) {
        const int ki = 2 * w + t;
        const int ni = si + ki;

        const _Float16* rowk =
            qkv + ((size_t)b * 4096 + (size_t)ni * 64) * 576 + CC + head * HD;
#pragma unroll
        for (int it = 0; it < 4; ++it) {
            const int idx = j + (it << 6);     // 0..255
            const int px  = idx >> 2;
            const int d8  = idx & 3;
            const _Float16* src = rowk + px * 576 + d8 * 8;
            f16x8 kf = *(const f16x8*)src;
            f16x8 vf = *(const f16x8*)(src + CC);
            uint4 ku = *(const uint4*)&kf;
            uint4 vu = *(const uint4*)&vf;
            unsigned* kd = kreg + (d8 * 4) * KSTR + px;
            kd[0]        = ku.x; kd[KSTR]     = ku.y;
            kd[2 * KSTR] = ku.z; kd[3 * KSTR] = ku.w;
            unsigned* vd = vreg + (d8 * 4) * KSTR + px;
            vd[0]        = vu.x; vd[KSTR]     = vu.y;
            vd[2 * KSTR] = vu.z; vd[3 * KSTR] = vu.w;
        }

        const float* rb = srpb + (ni - i + 6) * 13;
#pragma unroll
        for (int kj = 0; kj < 7; ++kj) {
            const int nj = sj + kj;
            const unsigned* kcol = kreg + nj;
            float d0 = 0.f, d1 = 0.f, d2 = 0.f, d3 = 0.f;
#pragma unroll
            for (int c = 0; c < 4; ++c) {
                d0 = hdot2(q2[c],      u2h(kcol[c * KSTR]),        d0);
                d1 = hdot2(q2[c + 4],  u2h(kcol[(c + 4) * KSTR]),  d1);
                d2 = hdot2(q2[c + 8],  u2h(kcol[(c + 8) * KSTR]),  d2);
                d3 = hdot2(q2[c + 12], u2h(kcol[(c + 12) * KSTR]), d3);
            }
            const float dot   = (d0 + d1) + (d2 + d3);
            const float logit = (dot + rb[nj - j + 6]) * temp;

            const float mn    = fmaxf(m, logit);
            const float alpha = __expf(m - mn);
            const float p     = __expf(logit - mn);
            l = l * alpha + p;
            m = mn;

            const unsigned* vcol = vreg + nj;
#pragma unroll
            for (int c = 0; c < 16; ++c) {
                const f16x2 h = u2h(vcol[c * KSTR]);
                acc[2 * c + 0] = fmaf(acc[2 * c + 0], alpha, p * (float)h[0]);
                acc[2 * c + 1] = fmaf(acc[2 * c + 1], alpha, p * (float)h[1]);
            }
        }
    }

    if (w > 0) {
        float* pp = (float*)(region[w]) + j * PSTRF;
#pragma unroll
        for (int d = 0; d < HD; ++d) pp[d] = acc[d];
        pp[32] = m; pp[33] = l;
    }
    __syncthreads();
    if (w == 0) {
#pragma unroll
        for (int ww = 1; ww < 4; ++ww) {
            const float* pp = (const float*)(region[ww]) + j * PSTRF;
            const float m2 = pp[32], l2 = pp[33];
            const float mn = fmaxf(m, m2);
            const float a1 = __expf(m - mn), a2 = __expf(m2 - mn);
            l = l * a1 + l2 * a2;
#pragma unroll
            for (int d = 0; d < HD; ++d) acc[d] = acc[d] * a1 + pp[d] * a2;
            m = mn;
        }
        const float inv = 1.f / l;
        _Float16* op = attn + pix * CC + head * HD;
#pragma unroll
        for (int c8 = 0; c8 < 4; ++c8) {
            f16x8 o;
#pragma unroll
            for (int e = 0; e < 8; ++e)
                o[e] = (_Float16)(acc[c8 * 8 + e] * inv);
            *(f16x8*)(op + c8 * 8) = o;
        }
    }
}

// ---------------------------------------------------------------------------
// GEMM2: out[8192,192] (f32) = attn[8192,192] (fp16) @ w_proj[192,192]^T
// A staged as direct fp16 copy (no convert). f32 C stored direct (64B segs).
// XCD-chunked grid: 384 = 8 * 48.
// ---------------------------------------------------------------------------
__global__ __launch_bounds__(256) void gemm_proj(const _Float16* __restrict__ A,
                                                 const float* __restrict__ Bw,
                                                 float* __restrict__ Cm) {
    __shared__ __align__(16) _Float16 As[64 * LDA];
    __shared__ __align__(16) _Float16 Bs[64 * LDA];

    const int t  = threadIdx.x;
    const int s  = blockIdx.x;            // 0..383
    const int kk = s >> 3;                // 0..47
    const int rowblk = (s & 7) * 16 + kk / 3;
    const int colblk = kk % 3;
    const int row0 = rowblk * 64;
    const int col0 = colblk * 64;

#pragma unroll
    for (int it = 0; it < 6; ++it) {
        const int idx = t + it * 256;
        const int r   = idx / 24;
        const int c8  = (idx % 24) * 8;
        f16x8 ha = *(const f16x8*)(A + (size_t)(row0 + r) * GK + c8);
        const float* pb = Bw + (size_t)(col0 + r) * GK + c8;
        float4 b0 = *(const float4*)pb;
        float4 b1 = *(const float4*)(pb + 4);
        f16x8 hb;
        hb[0] = (_Float16)b0.x; hb[1] = (_Float16)b0.y;
        hb[2] = (_Float16)b0.z; hb[3] = (_Float16)b0.w;
        hb[4] = (_Float16)b1.x; hb[5] = (_Float16)b1.y;
        hb[6] = (_Float16)b1.z; hb[7] = (_Float16)b1.w;
        *(f16x8*)&As[r * LDA + c8] = ha;
        *(f16x8*)&Bs[r * LDA + c8] = hb;
    }
    __syncthreads();

    const int wave = t >> 6;
    const int wr   = wave >> 1;
    const int wc   = wave & 1;
    const int lane = t & 63;
    const int ln   = lane & 15;
    const int quad = lane >> 4;

    f32x4 acc[2][2] = {};

#pragma unroll
    for (int ks = 0; ks < 6; ++ks) {
        const int k0 = ks * 32 + quad * 8;
        f16x8 af[2], bf[2];
#pragma unroll
        for (int mi = 0; mi < 2; ++mi)
            af[mi] = *(const f16x8*)&As[(wr * 32 + mi * 16 + ln) * LDA + k0];
#pragma unroll
        for (int ni = 0; ni < 2; ++ni)
            bf[ni] = *(const f16x8*)&Bs[(wc * 32 + ni * 16 + ln) * LDA + k0];
#pragma unroll
        for (int mi = 0; mi < 2; ++mi)
#pragma unroll
            for (int ni = 0; ni < 2; ++ni)
                acc[mi][ni] = __builtin_amdgcn_mfma_f32_16x16x32_f16(
                    af[mi], bf[ni], acc[mi][ni], 0, 0, 0);
    }

#pragma unroll
    for (int mi = 0; mi < 2; ++mi)
#pragma unroll
        for (int ni = 0; ni < 2; ++ni) {
            const int col = col0 + wc * 32 + ni * 16 + ln;
#pragma unroll
            for (int r = 0; r < 4; ++r) {
                const int row = row0 + wr * 32 + mi * 16 + quad * 4 + r;
                Cm[(size_t)row * CC + col] = acc[mi][ni][r];
            }
        }
}

// ---------------------------------------------------------------------------
extern "C" void kernel_launch(void* const* d_in, const int* in_sizes, int n_in,
                              void* d_out, int out_size, void* d_ws, size_t ws_size,
                              hipStream_t stream) {
    const float* x           = (const float*)d_in[0];
    const float* w_qkv       = (const float*)d_in[1];
    const float* rpb         = (const float*)d_in[2];
    const float* temperature = (const float*)d_in[3];
    const float* w_proj      = (const float*)d_in[4];
    float* out = (float*)d_out;

    _Float16* qkv  = (_Float16*)d_ws;                       // 8192*576 fp16
    _Float16* attn = qkv + (size_t)NPIX * 3 * CC;           // 8192*192 fp16

    // 1) qkv = x @ w_qkv^T  (fp16 out, q pre-scaled)
    gemm_qkv<<<dim3(1152), 256, 0, stream>>>(x, w_qkv, qkv);

    // 2) fused neighborhood attention (fp16 in/out)
    natten_v3<<<dim3(768), 256, 0, stream>>>(qkv, rpb, temperature, attn);

    // 3) out = attn @ w_proj^T  (fp32 out)
    gemm_proj<<<dim3(384), 256, 0, stream>>>(attn, w_proj, out);
}